// Round 4
// baseline (41.264 us; speedup 1.0000x reference)
//
#include <hip/hip_runtime.h>
#include <math.h>

#define OBS 2264
#define ACT 32
#define HID 4096
#define VOX 216
#define PRE (OBS - VOX)   // 2048
#define N4_OBS (OBS / 4)  // 566
#define N4_HID (HID / 4)  // 1024
#define ROWS0 8           // rows per block in gemv0
#define ROWS1 4           // rows per block in gemv1

// ---------------------------------------------------------------------------
// K1: conv3d chain (6 layers, SAME pad, ReLU) + input norm -> u[2264] in ws.
// ONE block, 256 threads. All layer indices compile-time (no runtime-indexed
// pointer arrays -> no scratch). Pointer selection via ternary chains
// (v_cndmask on registers, not memory).
// ---------------------------------------------------------------------------
__global__ __launch_bounds__(256) void conv_norm_kernel(
    const float* __restrict__ x,
    const float* __restrict__ cw0, const float* __restrict__ cb0,
    const float* __restrict__ cw1, const float* __restrict__ cb1,
    const float* __restrict__ cw2, const float* __restrict__ cb2,
    const float* __restrict__ cw3, const float* __restrict__ cb3,
    const float* __restrict__ cw4, const float* __restrict__ cb4,
    const float* __restrict__ cw5, const float* __restrict__ cb5,
    const float* __restrict__ in_shift, const float* __restrict__ in_scale,
    float* __restrict__ u)
{
    __shared__ float skw[6][27];
    __shared__ float skb[6];
    __shared__ float vbA[VOX], vbB[VOX];

    const int tid = threadIdx.x;

    // branchless-source weight staging: one load per thread, tid 0..161
    if (tid < 162) {
        const float* srcw = tid < 27  ? cw0
                          : tid < 54  ? cw1
                          : tid < 81  ? cw2
                          : tid < 108 ? cw3
                          : tid < 135 ? cw4 : cw5;
        const int base = tid < 27  ? 0
                       : tid < 54  ? 27
                       : tid < 81  ? 54
                       : tid < 108 ? 81
                       : tid < 135 ? 108 : 135;
        reinterpret_cast<float*>(skw)[tid] = srcw[tid - base];
    } else if (tid >= 192 && tid < 198) {
        const float* srcb = tid == 192 ? cb0
                          : tid == 193 ? cb1
                          : tid == 194 ? cb2
                          : tid == 195 ? cb3
                          : tid == 196 ? cb4 : cb5;
        skb[tid - 192] = srcb[0];
    }
    if (tid < VOX) vbA[tid] = x[PRE + tid];
    __syncthreads();

    const int d = tid / 36;
    const int h = (tid / 6) % 6;
    const int w = tid % 6;

#define CONV_LAYER(L, SRC, DST)                                              \
    if (tid < VOX) {                                                         \
        float acc = skb[L];                                                  \
        _Pragma("unroll") for (int kd = 0; kd < 3; ++kd) {                   \
            const int dd = d + kd - 1;                                       \
            if (dd >= 0 && dd <= 5) {                                        \
                _Pragma("unroll") for (int kh = 0; kh < 3; ++kh) {           \
                    const int hh = h + kh - 1;                               \
                    if (hh >= 0 && hh <= 5) {                                \
                        _Pragma("unroll") for (int kw2 = 0; kw2 < 3; ++kw2) {\
                            const int ww = w + kw2 - 1;                      \
                            if (ww >= 0 && ww <= 5)                          \
                                acc += skw[L][kd * 9 + kh * 3 + kw2]         \
                                     * SRC[dd * 36 + hh * 6 + ww];           \
                        }                                                    \
                    }                                                        \
                }                                                            \
            }                                                                \
        }                                                                    \
        DST[tid] = fmaxf(acc, 0.f);                                          \
    }                                                                        \
    __syncthreads();

    CONV_LAYER(0, vbA, vbB)
    CONV_LAYER(1, vbB, vbA)
    CONV_LAYER(2, vbA, vbB)
    CONV_LAYER(3, vbB, vbA)
    CONV_LAYER(4, vbA, vbB)
    CONV_LAYER(5, vbB, vbA)
#undef CONV_LAYER
    // result in vbA

    for (int i = tid; i < OBS; i += 256) {
        const float val = (i < PRE) ? x[i] : vbA[i - PRE];
        u[i] = (val - in_shift[i]) / (in_scale[i] + 1e-8f);
    }
}

// ---------------------------------------------------------------------------
// K2: GEMV W0 [4096,2264] + tanh. 512 blocks x 256 threads, 8 rows/block.
// u read directly from global (9 KB -> L1-resident after first row).
// ---------------------------------------------------------------------------
__global__ __launch_bounds__(256) void gemv0_kernel(
    const float* __restrict__ W, const float* __restrict__ b,
    const float* __restrict__ u, float* __restrict__ out)
{
    const int row0 = blockIdx.x * ROWS0;
    const int tid = threadIdx.x;
    const float4* __restrict__ u4 = reinterpret_cast<const float4*>(u);
    const float4* __restrict__ W4 = reinterpret_cast<const float4*>(W);

    float accs[ROWS0];
    #pragma unroll
    for (int r = 0; r < ROWS0; ++r) accs[r] = 0.f;

    for (int j = tid; j < N4_OBS; j += 256) {
        const float4 uv = u4[j];
        #pragma unroll
        for (int r = 0; r < ROWS0; ++r) {
            const float4 wv = W4[(size_t)(row0 + r) * N4_OBS + j];
            accs[r] += wv.x * uv.x + wv.y * uv.y + wv.z * uv.z + wv.w * uv.w;
        }
    }

    __shared__ float part[ROWS0][4];
    #pragma unroll
    for (int r = 0; r < ROWS0; ++r) {
        float a = accs[r];
        #pragma unroll
        for (int off = 32; off > 0; off >>= 1) a += __shfl_down(a, off, 64);
        if ((tid & 63) == 0) part[r][tid >> 6] = a;
    }
    __syncthreads();
    if (tid < ROWS0) {
        const float s = part[tid][0] + part[tid][1] + part[tid][2] + part[tid][3]
                      + b[row0 + tid];
        out[row0 + tid] = tanhf(s);
    }
}

// ---------------------------------------------------------------------------
// K3: GEMV W1 [4096,4096] + tanh, 4 rows/block (1024 blocks x 256).
// ---------------------------------------------------------------------------
__global__ __launch_bounds__(256) void gemv1_kernel(
    const float* __restrict__ W, const float* __restrict__ b,
    const float* __restrict__ u, float* __restrict__ out)
{
    const int row0 = blockIdx.x * ROWS1;
    const int tid = threadIdx.x;
    const float4* __restrict__ u4 = reinterpret_cast<const float4*>(u);
    const float4* __restrict__ W4 = reinterpret_cast<const float4*>(W);

    float accs[ROWS1] = {0.f, 0.f, 0.f, 0.f};
    for (int j = tid; j < N4_HID; j += 256) {
        const float4 uv = u4[j];
        #pragma unroll
        for (int r = 0; r < ROWS1; ++r) {
            const float4 wv = W4[(size_t)(row0 + r) * N4_HID + j];
            accs[r] += wv.x * uv.x + wv.y * uv.y + wv.z * uv.z + wv.w * uv.w;
        }
    }
    __shared__ float part[ROWS1][4];
    #pragma unroll
    for (int r = 0; r < ROWS1; ++r) {
        float a = accs[r];
        #pragma unroll
        for (int off = 32; off > 0; off >>= 1) a += __shfl_down(a, off, 64);
        if ((tid & 63) == 0) part[r][tid >> 6] = a;
    }
    __syncthreads();
    if (tid < ROWS1) {
        const float s = part[tid][0] + part[tid][1] + part[tid][2] + part[tid][3]
                      + b[row0 + tid];
        out[row0 + tid] = tanhf(s);
    }
}

// ---------------------------------------------------------------------------
// K4: final GEMV [32,4096] + output affine. 32 blocks x 1024 threads.
// ---------------------------------------------------------------------------
__global__ __launch_bounds__(1024) void gemv_out_kernel(
    const float* __restrict__ W, const float* __restrict__ b,
    const float* __restrict__ u,
    const float* __restrict__ oscale, const float* __restrict__ oshift,
    float* __restrict__ out)
{
    const int row = blockIdx.x;
    const int tid = threadIdx.x;
    const float4* __restrict__ Wr = reinterpret_cast<const float4*>(W + (size_t)row * HID);
    const float4* __restrict__ u4 = reinterpret_cast<const float4*>(u);

    const float4 wv = Wr[tid];
    const float4 uv = u4[tid];
    float a = wv.x * uv.x + wv.y * uv.y + wv.z * uv.z + wv.w * uv.w;

    #pragma unroll
    for (int off = 32; off > 0; off >>= 1) a += __shfl_down(a, off, 64);

    __shared__ float part[16];
    if ((tid & 63) == 0) part[tid >> 6] = a;
    __syncthreads();
    if (tid == 0) {
        float s = b[row];
        #pragma unroll
        for (int i = 0; i < 16; ++i) s += part[i];
        out[row] = s * oscale[row] + oshift[row];
    }
}

extern "C" void kernel_launch(void* const* d_in, const int* in_sizes, int n_in,
                              void* d_out, int out_size, void* d_ws, size_t ws_size,
                              hipStream_t stream) {
    const float* x = (const float*)d_in[0];

    const float* cw[6];
    const float* cb[6];
    if (in_sizes[2] == 1) {           // interleaved: x, cw0, cb0, cw1, cb1, ...
        for (int i = 0; i < 6; ++i) {
            cw[i] = (const float*)d_in[1 + 2 * i];
            cb[i] = (const float*)d_in[2 + 2 * i];
        }
    } else {                          // grouped: x, cw0..cw5, cb0..cb5
        for (int i = 0; i < 6; ++i) {
            cw[i] = (const float*)d_in[1 + i];
            cb[i] = (const float*)d_in[7 + i];
        }
    }
    const float* W0       = (const float*)d_in[13];
    const float* b0       = (const float*)d_in[14];
    const float* W1       = (const float*)d_in[15];
    const float* b1       = (const float*)d_in[16];
    const float* W2       = (const float*)d_in[17];
    const float* b2       = (const float*)d_in[18];
    const float* in_shift = (const float*)d_in[19];
    const float* in_scale = (const float*)d_in[20];
    const float* oshift   = (const float*)d_in[21];
    const float* oscale   = (const float*)d_in[22];

    float* ws = (float*)d_ws;
    float* u  = ws;            // [0, 2264) pad to 2304
    float* h0 = ws + 2304;     // [2304, 6400)
    float* h1 = ws + 6400;     // [6400, 10496)
    float* y  = (float*)d_out;

    conv_norm_kernel<<<1, 256, 0, stream>>>(
        x, cw[0], cb[0], cw[1], cb[1], cw[2], cb[2],
        cw[3], cb[3], cw[4], cb[4], cw[5], cb[5],
        in_shift, in_scale, u);

    gemv0_kernel<<<HID / ROWS0, 256, 0, stream>>>(W0, b0, u, h0);
    gemv1_kernel<<<HID / ROWS1, 256, 0, stream>>>(W1, b1, h0, h1);
    gemv_out_kernel<<<ACT, 1024, 0, stream>>>(W2, b2, h1, oscale, oshift, y);
}